// Round 23
// baseline (582.638 us; speedup 1.0000x reference)
//
#include <hip/hip_runtime.h>

typedef unsigned short u16;
typedef unsigned int   u32;
typedef __bf16 bf16_t;
typedef bf16_t bf16x4 __attribute__((ext_vector_type(4)));
typedef bf16_t bf16x8 __attribute__((ext_vector_type(8)));
typedef float  f32x4  __attribute__((ext_vector_type(4)));

// ---------- fp32 <-> bf16 helpers (RNE) ----------
__device__ __forceinline__ u16 f2bf(float f) {
  u32 u = __builtin_bit_cast(u32, f);
  u32 r = u + 0x7fffu + ((u >> 16) & 1u);
  return (u16)(r >> 16);
}
__device__ __forceinline__ float bf2f(u16 h) {
  u32 u = ((u32)h) << 16;
  return __builtin_bit_cast(float, u);
}

// async global->LDS, 16B per lane. LDS dest is wave-uniform base + lane*16.
__device__ __forceinline__ void gl_lds16(const u16* g, u16* l) {
  __builtin_amdgcn_global_load_lds(
      (const __attribute__((address_space(1))) u32*)g,
      (__attribute__((address_space(3))) u32*)l, 16, 0, 0);
}

// ---------- elementwise fp32 -> bf16 convert (4 el/thread) ----------
__global__ __launch_bounds__(256) void k_cvt(const float* __restrict__ in,
                                             u16* __restrict__ out, long n4) {
  long i = (long)blockIdx.x * 256 + threadIdx.x;
  if (i >= n4) return;
  float4 v = reinterpret_cast<const float4*>(in)[i];
  ushort4 o;
  o.x = f2bf(v.x); o.y = f2bf(v.y); o.z = f2bf(v.z); o.w = f2bf(v.w);
  reinterpret_cast<ushort4*>(out)[i] = o;
}

// ---------- W[K][N] fp32 -> Wt[N][K] bf16 (32x32 tiles) ----------
__global__ __launch_bounds__(256) void k_transpose_cvt(const float* __restrict__ W,
                                                       u16* __restrict__ Wt,
                                                       int K, int N) {
  __shared__ u16 tile[32][33];
  int n0 = blockIdx.x * 32, k0 = blockIdx.y * 32;
  int tx = threadIdx.x & 31, ty = threadIdx.x >> 5;
#pragma unroll
  for (int i = 0; i < 4; ++i) {
    int k = ty + i * 8;
    tile[k][tx] = f2bf(W[(size_t)(k0 + k) * N + n0 + tx]);
  }
  __syncthreads();
#pragma unroll
  for (int i = 0; i < 4; ++i) {
    int n = ty + i * 8;
    Wt[(size_t)(n0 + n) * K + k0 + tx] = tile[tx][n];
  }
}

// ---------- bf16 V[key][64] (strided) -> Vt[64][Tk] per head ----------
__global__ __launch_bounds__(256) void k_vtrans(const u16* __restrict__ in,
                                                u16* __restrict__ out,
                                                long long ibs, int ihs, int irs,
                                                int Tk) {
  __shared__ u16 t[64][72];
  const int tid = threadIdx.x;
  const int head = blockIdx.y;
  const int b = head >> 4, h = head & 15;
  const int kt = blockIdx.x * 64;
  const u16* ip = in + (size_t)b * ibs + (size_t)h * ihs;
  u16* op = out + (size_t)head * 64 * Tk;
#pragma unroll
  for (int i = 0; i < 2; ++i) {
    int c = i * 256 + tid;
    int key = c >> 3, d = (c & 7) * 8;
    *reinterpret_cast<uint4*>(&t[key][d]) =
        *reinterpret_cast<const uint4*>(ip + (size_t)(kt + key) * irs + d);
  }
  __syncthreads();
#pragma unroll
  for (int i = 0; i < 2; ++i) {
    int c = i * 256 + tid;
    int d = c >> 3, k8 = (c & 7) * 8;
    ushort4 lo, hi;
    lo.x = t[k8 + 0][d]; lo.y = t[k8 + 1][d]; lo.z = t[k8 + 2][d]; lo.w = t[k8 + 3][d];
    hi.x = t[k8 + 4][d]; hi.y = t[k8 + 5][d]; hi.z = t[k8 + 6][d]; hi.w = t[k8 + 7][d];
    uint4 o;
    o.x = ((u32)lo.y << 16) | lo.x; o.y = ((u32)lo.w << 16) | lo.z;
    o.z = ((u32)hi.y << 16) | hi.x; o.w = ((u32)hi.w << 16) | hi.z;
    *reinterpret_cast<uint4*>(op + (size_t)d * Tk + kt + k8) = o;
  }
}

// ---------- GEMM 128x128: 2-phase double-buffered gload_lds ----------
template<int RELU>
__global__ __launch_bounds__(256) void k_gemm_bt(
    const u16* __restrict__ A, const u16* __restrict__ Bt,
    const float* __restrict__ bias, u16* __restrict__ C,
    int M, int N, int K)
{
  __shared__ __align__(16) u16 As[2][128 * 64];
  __shared__ __align__(16) u16 Bs[2][128 * 64];
  const int tid = threadIdx.x;
  const int lane = tid & 63, wid = tid >> 6;
  const int wr = wid >> 1, wc = wid & 1;
  const int l15 = lane & 15, g = lane >> 4;
  const int bm = blockIdx.x * 128, bn = blockIdx.y * 128;
  const int srow = lane >> 3, scol = (lane & 7) * 8;

  f32x4 acc[4][4] = {};

  auto stage = [&](int buf, int kt) {
#pragma unroll
    for (int i = 0; i < 4; ++i) {
      int ch = wid * 4 + i;                     // chunk: 8 rows of 64
      gl_lds16(A  + (size_t)(bm + ch * 8 + srow) * K + kt + scol, &As[buf][ch * 512]);
      gl_lds16(Bt + (size_t)(bn + ch * 8 + srow) * K + kt + scol, &Bs[buf][ch * 512]);
    }
  };

  stage(0, 0);
  __syncthreads();
  int cur = 0;
  for (int kt = 0; kt < K; kt += 64) {
    if (kt + 64 < K) stage(cur ^ 1, kt + 64);   // loads fly across MFMA below
#pragma unroll
    for (int ks = 0; ks < 2; ++ks) {
      bf16x8 af[4], bfr[4];
#pragma unroll
      for (int m = 0; m < 4; ++m)
        af[m] = *reinterpret_cast<const bf16x8*>(&As[cur][(wr * 64 + m * 16 + l15) * 64 + ks * 32 + g * 8]);
#pragma unroll
      for (int n = 0; n < 4; ++n)
        bfr[n] = *reinterpret_cast<const bf16x8*>(&Bs[cur][(wc * 64 + n * 16 + l15) * 64 + ks * 32 + g * 8]);
      __builtin_amdgcn_s_setprio(1);
#pragma unroll
      for (int m = 0; m < 4; ++m)
#pragma unroll
        for (int n = 0; n < 4; ++n)
          acc[m][n] = __builtin_amdgcn_mfma_f32_16x16x32_bf16(af[m], bfr[n], acc[m][n], 0, 0, 0);
      __builtin_amdgcn_s_setprio(0);
    }
    __syncthreads();
    cur ^= 1;
  }
  // epilogue: preload bias per n, store row-sequential
  float bv[4];
#pragma unroll
  for (int n = 0; n < 4; ++n) bv[n] = bias[bn + wc * 64 + n * 16 + l15];
#pragma unroll
  for (int m = 0; m < 4; ++m)
#pragma unroll
    for (int r = 0; r < 4; ++r) {
      int row = bm + wr * 64 + m * 16 + g * 4 + r;
#pragma unroll
      for (int n = 0; n < 4; ++n) {
        float v = acc[m][n][r] + bv[n];
        if (RELU) v = fmaxf(v, 0.f);
        C[(size_t)row * N + bn + wc * 64 + n * 16 + l15] = f2bf(v);
      }
    }
}

// ---------- GEMM 256x256, 8 waves, counted-vmcnt 4-phase + T2 XOR swizzle ----------
template<int RELU>
__global__ __launch_bounds__(512, 1) void k_gemm256(
    const u16* __restrict__ A, const u16* __restrict__ Bt,
    const float* __restrict__ bias, u16* __restrict__ C,
    int M, int N, int K)
{
  __shared__ __align__(16) u16 lds[65536];      // 128 KiB: [buf][A|B][slab][64x64]
  const int tid = threadIdx.x;
  const int lane = tid & 63, wid = tid >> 6;
  const int wr = wid >> 2, wc = wid & 3;        // 2 x 4 wave grid
  const int l15 = lane & 15, g = lane >> 4;
  const int bm = blockIdx.x * 256, bn = blockIdx.y * 256;
  const int srow = tid >> 3;                              // 0..63 within slab
  const int swcol = (((tid & 7) ^ ((tid >> 3) & 7)) * 8); // inverse-swizzled source col
  const int swr = l15 & 7;                                // read-side row xor key

  f32x4 acc[8][4] = {};

  auto stageA = [&](int buf, int j, int kt) {
    gl_lds16(A + (size_t)(bm + j * 64 + srow) * K + kt + swcol,
             lds + buf * 32768 + j * 4096 + wid * 512);
  };
  auto stageB = [&](int buf, int j, int kt) {
    gl_lds16(Bt + (size_t)(bn + j * 64 + srow) * K + kt + swcol,
             lds + buf * 32768 + 16384 + j * 4096 + wid * 512);
  };

  // prologue: tile 0, steady-state issue order
  stageB(0, 0, 0); stageB(0, 1, 0); stageB(0, 2, 0); stageB(0, 3, 0);
  stageA(0, 0, 0); stageA(0, 2, 0); stageA(0, 1, 0); stageA(0, 3, 0);
  asm volatile("s_waitcnt vmcnt(2)" ::: "memory");
  __builtin_amdgcn_s_barrier();

  int cur = 0;
  for (int kt = 0; kt < K; kt += 64) {
    const u16* Ab = lds + cur * 32768;
    const u16* Bb = lds + cur * 32768 + 16384;
    const bool pre = (kt + 64 < K);
    const int nb = cur ^ 1;
    bf16x8 af[4][2], bflo[2][2], bfhi[2][2];

    // ---- phase 0: m0-3 x n0-1 ; issue B0,B1(t+1) ----
#pragma unroll
    for (int m = 0; m < 4; ++m)
#pragma unroll
      for (int ks = 0; ks < 2; ++ks)
        af[m][ks] = *reinterpret_cast<const bf16x8*>(
            &Ab[(2 * wr) * 4096 + (m * 16 + l15) * 64 + (((ks * 4 + g) ^ swr) * 8)]);
#pragma unroll
    for (int n = 0; n < 2; ++n)
#pragma unroll
      for (int ks = 0; ks < 2; ++ks)
        bflo[n][ks] = *reinterpret_cast<const bf16x8*>(
            &Bb[wc * 4096 + (n * 16 + l15) * 64 + (((ks * 4 + g) ^ swr) * 8)]);
    if (pre) { stageB(nb, 0, kt + 64); stageB(nb, 1, kt + 64); }
    __builtin_amdgcn_s_setprio(1);
#pragma unroll
    for (int m = 0; m < 4; ++m)
#pragma unroll
      for (int n = 0; n < 2; ++n)
#pragma unroll
        for (int ks = 0; ks < 2; ++ks)
          acc[m][n] = __builtin_amdgcn_mfma_f32_16x16x32_bf16(af[m][ks], bflo[n][ks], acc[m][n], 0, 0, 0);
    __builtin_amdgcn_s_setprio(0);
    __builtin_amdgcn_s_barrier();

    // ---- phase 1: m0-3 x n2-3 ; issue B2,B3(t+1) ; wait A1,A3(t) ----
#pragma unroll
    for (int n = 0; n < 2; ++n)
#pragma unroll
      for (int ks = 0; ks < 2; ++ks)
        bfhi[n][ks] = *reinterpret_cast<const bf16x8*>(
            &Bb[wc * 4096 + ((n + 2) * 16 + l15) * 64 + (((ks * 4 + g) ^ swr) * 8)]);
    if (pre) { stageB(nb, 2, kt + 64); stageB(nb, 3, kt + 64); }
    __builtin_amdgcn_s_setprio(1);
#pragma unroll
    for (int m = 0; m < 4; ++m)
#pragma unroll
      for (int n = 0; n < 2; ++n)
#pragma unroll
        for (int ks = 0; ks < 2; ++ks)
          acc[m][n + 2] = __builtin_amdgcn_mfma_f32_16x16x32_bf16(af[m][ks], bfhi[n][ks], acc[m][n + 2], 0, 0, 0);
    __builtin_amdgcn_s_setprio(0);
    if (pre) { asm volatile("s_waitcnt vmcnt(4)" ::: "memory"); }
    else     { asm volatile("s_waitcnt vmcnt(0)" ::: "memory"); }
    __builtin_amdgcn_s_barrier();

    // ---- phase 2: m4-7 x n2-3 (A slabs 2wr+1) ; issue A0,A2(t+1) ----
#pragma unroll
    for (int m = 0; m < 4; ++m)
#pragma unroll
      for (int ks = 0; ks < 2; ++ks)
        af[m][ks] = *reinterpret_cast<const bf16x8*>(
            &Ab[(2 * wr + 1) * 4096 + (m * 16 + l15) * 64 + (((ks * 4 + g) ^ swr) * 8)]);
    if (pre) { stageA(nb, 0, kt + 64); stageA(nb, 2, kt + 64); }
    __builtin_amdgcn_s_setprio(1);
#pragma unroll
    for (int m = 0; m < 4; ++m)
#pragma unroll
      for (int n = 0; n < 2; ++n)
#pragma unroll
        for (int ks = 0; ks < 2; ++ks)
          acc[m + 4][n + 2] = __builtin_amdgcn_mfma_f32_16x16x32_bf16(af[m][ks], bfhi[n][ks], acc[m + 4][n + 2], 0, 0, 0);
    __builtin_amdgcn_s_setprio(0);
    __builtin_amdgcn_s_barrier();

    // ---- phase 3: m4-7 x n0-1 ; issue A1,A3(t+1) ; boundary wait ----
    if (pre) { stageA(nb, 1, kt + 64); stageA(nb, 3, kt + 64); }
    __builtin_amdgcn_s_setprio(1);
#pragma unroll
    for (int m = 0; m < 4; ++m)
#pragma unroll
      for (int n = 0; n < 2; ++n)
#pragma unroll
        for (int ks = 0; ks < 2; ++ks)
          acc[m + 4][n] = __builtin_amdgcn_mfma_f32_16x16x32_bf16(af[m][ks], bflo[n][ks], acc[m + 4][n], 0, 0, 0);
    __builtin_amdgcn_s_setprio(0);
    asm volatile("s_waitcnt vmcnt(2)" ::: "memory");
    __builtin_amdgcn_s_barrier();
    cur ^= 1;
  }

  // epilogue: preload bias per n, store row-sequential (full-line coalescing)
  float bv[4];
#pragma unroll
  for (int n = 0; n < 4; ++n) bv[n] = bias[bn + wc * 64 + n * 16 + l15];
#pragma unroll
  for (int m = 0; m < 8; ++m)
#pragma unroll
    for (int r = 0; r < 4; ++r) {
      int row = bm + wr * 128 + m * 16 + g * 4 + r;
#pragma unroll
      for (int n = 0; n < 4; ++n) {
        float v = acc[m][n][r] + bv[n];
        if (RELU) v = fmaxf(v, 0.f);
        C[(size_t)row * N + bn + wc * 64 + n * 16 + l15] = f2bf(v);
      }
    }
}

// ---------- split-K GEMM 256x256 on the counted-vmcnt skeleton: f32 partials ----------
__global__ __launch_bounds__(512, 1) void k_gemm256sk(
    const u16* __restrict__ A, const u16* __restrict__ Bt,
    float* __restrict__ P,
    int M, int N, int Kfull, int Kchunk)
{
  __shared__ __align__(16) u16 lds[65536];
  const int tid = threadIdx.x;
  const int lane = tid & 63, wid = tid >> 6;
  const int wr = wid >> 2, wc = wid & 3;
  const int l15 = lane & 15, g = lane >> 4;
  const int bm = blockIdx.x * 256, bn = blockIdx.y * 256;
  const int k0 = blockIdx.z * Kchunk;
  float* Pz = P + (size_t)blockIdx.z * M * N;
  const int srow = tid >> 3;
  const int swcol = (((tid & 7) ^ ((tid >> 3) & 7)) * 8);
  const int swr = l15 & 7;

  f32x4 acc[8][4] = {};

  auto stageA = [&](int buf, int j, int kt) {
    gl_lds16(A + (size_t)(bm + j * 64 + srow) * Kfull + k0 + kt + swcol,
             lds + buf * 32768 + j * 4096 + wid * 512);
  };
  auto stageB = [&](int buf, int j, int kt) {
    gl_lds16(Bt + (size_t)(bn + j * 64 + srow) * Kfull + k0 + kt + swcol,
             lds + buf * 32768 + 16384 + j * 4096 + wid * 512);
  };

  stageB(0, 0, 0); stageB(0, 1, 0); stageB(0, 2, 0); stageB(0, 3, 0);
  stageA(0, 0, 0); stageA(0, 2, 0); stageA(0, 1, 0); stageA(0, 3, 0);
  asm volatile("s_waitcnt vmcnt(2)" ::: "memory");
  __builtin_amdgcn_s_barrier();

  int cur = 0;
  for (int kt = 0; kt < Kchunk; kt += 64) {
    const u16* Ab = lds + cur * 32768;
    const u16* Bb = lds + cur * 32768 + 16384;
    const bool pre = (kt + 64 < Kchunk);
    const int nb = cur ^ 1;
    bf16x8 af[4][2], bflo[2][2], bfhi[2][2];

    // ---- phase 0 ----
#pragma unroll
    for (int m = 0; m < 4; ++m)
#pragma unroll
      for (int ks = 0; ks < 2; ++ks)
        af[m][ks] = *reinterpret_cast<const bf16x8*>(
            &Ab[(2 * wr) * 4096 + (m * 16 + l15) * 64 + (((ks * 4 + g) ^ swr) * 8)]);
#pragma unroll
    for (int n = 0; n < 2; ++n)
#pragma unroll
      for (int ks = 0; ks < 2; ++ks)
        bflo[n][ks] = *reinterpret_cast<const bf16x8*>(
            &Bb[wc * 4096 + (n * 16 + l15) * 64 + (((ks * 4 + g) ^ swr) * 8)]);
    if (pre) { stageB(nb, 0, kt + 64); stageB(nb, 1, kt + 64); }
    __builtin_amdgcn_s_setprio(1);
#pragma unroll
    for (int m = 0; m < 4; ++m)
#pragma unroll
      for (int n = 0; n < 2; ++n)
#pragma unroll
        for (int ks = 0; ks < 2; ++ks)
          acc[m][n] = __builtin_amdgcn_mfma_f32_16x16x32_bf16(af[m][ks], bflo[n][ks], acc[m][n], 0, 0, 0);
    __builtin_amdgcn_s_setprio(0);
    __builtin_amdgcn_s_barrier();

    // ---- phase 1 ----
#pragma unroll
    for (int n = 0; n < 2; ++n)
#pragma unroll
      for (int ks = 0; ks < 2; ++ks)
        bfhi[n][ks] = *reinterpret_cast<const bf16x8*>(
            &Bb[wc * 4096 + ((n + 2) * 16 + l15) * 64 + (((ks * 4 + g) ^ swr) * 8)]);
    if (pre) { stageB(nb, 2, kt + 64); stageB(nb, 3, kt + 64); }
    __builtin_amdgcn_s_setprio(1);
#pragma unroll
    for (int m = 0; m < 4; ++m)
#pragma unroll
      for (int n = 0; n < 2; ++n)
#pragma unroll
        for (int ks = 0; ks < 2; ++ks)
          acc[m][n + 2] = __builtin_amdgcn_mfma_f32_16x16x32_bf16(af[m][ks], bfhi[n][ks], acc[m][n + 2], 0, 0, 0);
    __builtin_amdgcn_s_setprio(0);
    if (pre) { asm volatile("s_waitcnt vmcnt(4)" ::: "memory"); }
    else     { asm volatile("s_waitcnt vmcnt(0)" ::: "memory"); }
    __builtin_amdgcn_s_barrier();

    // ---- phase 2 ----
#pragma unroll
    for (int m = 0; m < 4; ++m)
#pragma unroll
      for (int ks = 0; ks < 2; ++ks)
        af[m][ks] = *reinterpret_cast<const bf16x8*>(
            &Ab[(2 * wr + 1) * 4096 + (m * 16 + l15) * 64 + (((ks * 4 + g) ^ swr) * 8)]);
    if (pre) { stageA(nb, 0, kt + 64); stageA(nb, 2, kt + 64); }
    __builtin_amdgcn_s_setprio(1);
#pragma unroll
    for (int m = 0; m < 4; ++m)
#pragma unroll
      for (int n = 0; n < 2; ++n)
#pragma unroll
        for (int ks = 0; ks < 2; ++ks)
          acc[m + 4][n + 2] = __builtin_amdgcn_mfma_f32_16x16x32_bf16(af[m][ks], bfhi[n][ks], acc[m + 4][n + 2], 0, 0, 0);
    __builtin_amdgcn_s_setprio(0);
    __builtin_amdgcn_s_barrier();

    // ---- phase 3 ----
    if (pre) { stageA(nb, 1, kt + 64); stageA(nb, 3, kt + 64); }
    __builtin_amdgcn_s_setprio(1);
#pragma unroll
    for (int m = 0; m < 4; ++m)
#pragma unroll
      for (int n = 0; n < 2; ++n)
#pragma unroll
        for (int ks = 0; ks < 2; ++ks)
          acc[m + 4][n] = __builtin_amdgcn_mfma_f32_16x16x32_bf16(af[m][ks], bflo[n][ks], acc[m + 4][n], 0, 0, 0);
    __builtin_amdgcn_s_setprio(0);
    asm volatile("s_waitcnt vmcnt(2)" ::: "memory");
    __builtin_amdgcn_s_barrier();
    cur ^= 1;
  }

  // epilogue: f32 partials, row-sequential
#pragma unroll
  for (int m = 0; m < 8; ++m)
#pragma unroll
    for (int r = 0; r < 4; ++r) {
      int row = bm + wr * 128 + m * 16 + g * 4 + r;
#pragma unroll
      for (int n = 0; n < 4; ++n)
        Pz[(size_t)row * N + bn + wc * 64 + n * 16 + l15] = acc[m][n][r];
    }
}

// ---------- flash attention v16: KVBLK=128, 8 waves, 2 qsets, JIT P-frags ----------
// Half the barriers of v15; per-kc just-in-time P fragments keep VGPR in check.
__global__ __launch_bounds__(512) void k_flash2(
    const u16* __restrict__ Qg, const u16* __restrict__ Kg, const u16* __restrict__ VTg,
    u16* __restrict__ Og,
    long long qbs, int qhs, int qrs,
    long long kbs, int khs, int krs,
    long long obs, int ohs, int ors,
    int Tk)
{
  __shared__ __align__(16) u16 Ks[128][72];
  __shared__ __align__(16) u16 Vs[64][136];     // Vs[d][key 0..127]
  const int tid = threadIdx.x;
  const int lane = tid & 63, wid = tid >> 6;    // wid 0..7
  const int l15 = lane & 15, g = lane >> 4;
  const int head = blockIdx.x;                  // head on x -> XCD-local
  const int b = head >> 4, h = head & 15;
  const int srow = tid >> 3, scol = (tid & 7) * 8;    // K: 64 rows/issue
  const int vrow = tid >> 4, vcol = (tid & 15) * 8;   // V: 32 rows/issue

  const u16* Q  = Qg + (size_t)b * qbs + (size_t)h * qhs;
  const u16* Kp = Kg + (size_t)b * kbs + (size_t)h * khs;
  const u16* Vp = VTg + (size_t)head * 64 * Tk;
  u16* Op = Og + (size_t)b * obs + (size_t)h * ohs;

  const int q0 = blockIdx.y * 256 + wid * 32;  // wave owns rows [q0, q0+32)
  const float SCL = 0.125f * 1.44269504f;      // folded into Q below

  bf16x8 qf0[2], qf1[2];
#pragma unroll
  for (int ks = 0; ks < 2; ++ks) {
    bf16x8 r0 = *reinterpret_cast<const bf16x8*>(Q + (size_t)(q0 + l15) * qrs + ks * 32 + g * 8);
    bf16x8 r1 = *reinterpret_cast<const bf16x8*>(Q + (size_t)(q0 + 16 + l15) * qrs + ks * 32 + g * 8);
#pragma unroll
    for (int j = 0; j < 8; ++j) {
      qf0[ks][j] = (bf16_t)((float)r0[j] * SCL);
      qf1[ks][j] = (bf16_t)((float)r1[j] * SCL);
    }
  }
  bf16x8 ones;
#pragma unroll
  for (int j = 0; j < 8; ++j) ones[j] = (bf16_t)1.0f;

  f32x4 oacc0[4] = {}, oacc1[4] = {};
  f32x4 lacc0 = {}, lacc1 = {};

  uint4 ka0, ka1, va0, va1, kb0, kb1, vb0, vb1;

  auto load_set = [&](int kt, uint4& k0, uint4& k1, uint4& v0, uint4& v1) {
    k0 = *reinterpret_cast<const uint4*>(Kp + (size_t)(kt + srow) * krs + scol);
    k1 = *reinterpret_cast<const uint4*>(Kp + (size_t)(kt + 64 + srow) * krs + scol);
    v0 = *reinterpret_cast<const uint4*>(Vp + (size_t)vrow * Tk + kt + vcol);
    v1 = *reinterpret_cast<const uint4*>(Vp + (size_t)(vrow + 32) * Tk + kt + vcol);
  };

  auto tile = [&](const uint4& k0, const uint4& k1, const uint4& v0, const uint4& v1,
                  int ktn, uint4& nk0, uint4& nk1, uint4& nv0, uint4& nv1) {
    __syncthreads();   // previous compute done reading LDS
    *reinterpret_cast<uint4*>(&Ks[srow][scol])       = k0;
    *reinterpret_cast<uint4*>(&Ks[64 + srow][scol])  = k1;
    *reinterpret_cast<uint4*>(&Vs[vrow][vcol])       = v0;
    *reinterpret_cast<uint4*>(&Vs[vrow + 32][vcol])  = v1;
    load_set(ktn, nk0, nk1, nv0, nv1);  // T14: next tile flies under compute
    __syncthreads();   // staging visible

    // QK^T for both qsets over 128 keys; each kf read feeds two MFMAs
    f32x4 sc0[8] = {}, sc1[8] = {};
    __builtin_amdgcn_s_setprio(1);
#pragma unroll
    for (int ks = 0; ks < 2; ++ks)
#pragma unroll
      for (int kb2 = 0; kb2 < 8; ++kb2) {
        bf16x8 kf = *reinterpret_cast<const bf16x8*>(&Ks[kb2 * 16 + l15][ks * 32 + g * 8]);
        sc0[kb2] = __builtin_amdgcn_mfma_f32_16x16x32_bf16(kf, qf0[ks], sc0[kb2], 0, 0, 0);
        sc1[kb2] = __builtin_amdgcn_mfma_f32_16x16x32_bf16(kf, qf1[ks], sc1[kb2], 0, 0, 0);
      }
    __builtin_amdgcn_s_setprio(0);

    // PV per kc: JIT P fragments (slot bijection F(g,j)), shared vf
#pragma unroll
    for (int kc = 0; kc < 4; ++kc) {
      bf16x8 pf0, pf1;
#pragma unroll
      for (int r = 0; r < 4; ++r) {
        pf0[r]     = (bf16_t)__builtin_amdgcn_exp2f(sc0[2 * kc][r]);
        pf0[4 + r] = (bf16_t)__builtin_amdgcn_exp2f(sc0[2 * kc + 1][r]);
        pf1[r]     = (bf16_t)__builtin_amdgcn_exp2f(sc1[2 * kc][r]);
        pf1[4 + r] = (bf16_t)__builtin_amdgcn_exp2f(sc1[2 * kc + 1][r]);
      }
      __builtin_amdgcn_s_setprio(1);
#pragma unroll
      for (int nb = 0; nb < 4; ++nb) {
        bf16x4 vlo = *reinterpret_cast<const bf16x4*>(&Vs[nb * 16 + l15][kc * 32 + 4 * g]);
        bf16x4 vhi = *reinterpret_cast<const bf16x4*>(&Vs[nb * 16 + l15][kc * 32 + 16 + 4 * g]);
        bf16x8 vf;
#pragma unroll
        for (int j = 0; j < 4; ++j) { vf[j] = vlo[j]; vf[4 + j] = vhi[j]; }
        oacc0[nb] = __builtin_amdgcn_mfma_f32_16x16x32_bf16(pf0, vf, oacc0[nb], 0, 0, 0);
        oacc1[nb] = __builtin_amdgcn_mfma_f32_16x16x32_bf16(pf1, vf, oacc1[nb], 0, 0, 0);
      }
      lacc0 = __builtin_amdgcn_mfma_f32_16x16x32_bf16(pf0, ones, lacc0, 0, 0, 0);
      lacc1 = __builtin_amdgcn_mfma_f32_16x16x32_bf16(pf1, ones, lacc1, 0, 0, 0);
      __builtin_amdgcn_s_setprio(0);
    }
  };

  load_set(0, ka0, ka1, va0, va1);
  for (int kt = 0; kt < Tk; kt += 256) {
    tile(ka0, ka1, va0, va1, kt + 128, kb0, kb1, vb0, vb1);
    int ktn = (kt + 256 < Tk) ? kt + 256 : 0;   // last prefetch harmless
    tile(kb0, kb1, vb0, vb1, ktn, ka0, ka1, va0, va1);
  }

  // epilogue: lacc[r] holds l for qrow 4g+r directly
#pragma unroll
  for (int r = 0; r < 4; ++r) {
    float inv0 = 1.f / lacc0[r];
    float inv1 = 1.f / lacc1[r];
#pragma unroll
    for (int nb = 0; nb < 4; ++nb) {
      Op[(size_t)(q0 + g * 4 + r) * ors + nb * 16 + l15]      = f2bf(oacc0[nb][r] * inv0);
      Op[(size_t)(q0 + 16 + g * 4 + r) * ors + nb * 16 + l15] = f2bf(oacc1[nb][r] * inv1);
    }
  }
}

// ---------- fused add + LayerNorm over D=1024 (one row per block) ----------
__device__ __forceinline__ void load4v(const float* p, float* v) {
  float4 t = *reinterpret_cast<const float4*>(p);
  v[0] = t.x; v[1] = t.y; v[2] = t.z; v[3] = t.w;
}
__device__ __forceinline__ void load4v(const u16* p, float* v) {
  ushort4 t = *reinterpret_cast<const ushort4*>(p);
  v[0] = bf2f(t.x); v[1] = bf2f(t.y); v[2] = bf2f(t.z); v[3] = bf2f(t.w);
}
__device__ __forceinline__ void store4v(float* p, const float* v) {
  float4 t; t.x = v[0]; t.y = v[1]; t.z = v[2]; t.w = v[3];
  *reinterpret_cast<float4*>(p) = t;
}
__device__ __forceinline__ void store4v(u16* p, const float* v) {
  ushort4 t; t.x = f2bf(v[0]); t.y = f2bf(v[1]); t.z = f2bf(v[2]); t.w = f2bf(v[3]);
  *reinterpret_cast<ushort4*>(p) = t;
}

__device__ __forceinline__ void ln_core(float* v, int tid, const float* gamma,
                                        const float* beta, float* o) {
  float s = v[0] + v[1] + v[2] + v[3];
  float q = v[0]*v[0] + v[1]*v[1] + v[2]*v[2] + v[3]*v[3];
#pragma unroll
  for (int off = 32; off > 0; off >>= 1) {
    s += __shfl_down(s, off);
    q += __shfl_down(q, off);
  }
  __shared__ float sh[8];
  const int lane = tid & 63, wid = tid >> 6;
  if (lane == 0) { sh[wid] = s; sh[4 + wid] = q; }
  __syncthreads();
  s = sh[0] + sh[1] + sh[2] + sh[3];
  q = sh[4] + sh[5] + sh[6] + sh[7];
  float mean = s * (1.f / 1024.f);
  float var = q * (1.f / 1024.f) - mean * mean;
  float inv = 1.f / sqrtf(var + 1e-5f);
  float gv[4], bv[4];
  load4v(gamma + tid * 4, gv);
  load4v(beta + tid * 4, bv);
#pragma unroll
  for (int j = 0; j < 4; ++j) o[j] = gv[j] * (v[j] - mean) * inv + bv[j];
}

template<typename TRES, typename TOUT>
__global__ __launch_bounds__(256) void k_add_ln(
    const u16* __restrict__ X, const TRES* __restrict__ R,
    const float* __restrict__ gamma, const float* __restrict__ beta,
    TOUT* __restrict__ Out)
{
  const int row = blockIdx.x;
  const int tid = threadIdx.x;
  const size_t base = (size_t)row * 1024 + tid * 4;
  float x[4], rr[4], v[4], o[4];
  load4v(X + base, x);
  load4v(R + base, rr);
#pragma unroll
  for (int j = 0; j < 4; ++j) v[j] = x[j] + rr[j];
  ln_core(v, tid, gamma, beta, o);
  store4v(Out + base, o);
}

// sum of 2 f32 split-K partials + bias + residual, then LN -> f32 out
__global__ __launch_bounds__(256) void k_add_ln_ff(
    const float* __restrict__ P0, const float* __restrict__ P1,
    const float* __restrict__ bias, const u16* __restrict__ R,
    const float* __restrict__ gamma, const float* __restrict__ beta,
    float* __restrict__ Out)
{
  const int row = blockIdx.x;
  const int tid = threadIdx.x;
  const size_t base = (size_t)row * 1024 + tid * 4;
  float p0[4], p1[4], bb[4], rr[4], v[4], o[4];
  load4v(P0 + base, p0);
  load4v(P1 + base, p1);
  load4v(bias + tid * 4, bb);
  load4v(R + base, rr);
#pragma unroll
  for (int j = 0; j < 4; ++j) v[j] = p0[j] + p1[j] + bb[j] + rr[j];
  ln_core(v, tid, gamma, beta, o);
  store4v(Out + base, o);
}

// ---------- driver ----------
extern "C" void kernel_launch(void* const* d_in, const int* in_sizes, int n_in,
                              void* d_out, int out_size, void* d_ws, size_t ws_size,
                              hipStream_t stream)
{
  (void)in_sizes; (void)n_in; (void)out_size; (void)ws_size;
  const float* x_enc  = (const float*)d_in[0];
  const float* x_dec  = (const float*)d_in[1];
  const float* qkv_w  = (const float*)d_in[2];
  const float* qkv_b  = (const float*)d_in[3];
  const float* sa_o_w = (const float*)d_in[4];
  const float* sa_o_b = (const float*)d_in[5];
  const float* g1     = (const float*)d_in[6];
  const float* be1    = (const float*)d_in[7];
  const float* q_w    = (const float*)d_in[8];
  const float* q_b    = (const float*)d_in[9];
  const float* kv_w   = (const float*)d_in[10];
  const float* kv_b   = (const float*)d_in[11];
  const float* ca_o_w = (const float*)d_in[12];
  const float* ca_o_b = (const float*)d_in[13];
  const float* g2     = (const float*)d_in[14];
  const float* be2    = (const float*)d_in[15];
  const float* ff_w1  = (const float*)d_in[16];
  const float* ff_b1  = (const float*)d_in[17];
  const float* ff_w2  = (const float*)d_in[18];
  const float* ff_b2  = (const float*)d_in[19];
  const float* g3     = (const float*)d_in[20];
  const float* be3    = (const float*)d_in[21];
  float* out = (float*)d_out;

  u16* Wb = (u16*)d_ws;
  const size_t O_WQKV = 0;
  const size_t O_WSAO = O_WQKV + (size_t)3072 * 1024;
  const size_t O_WQ   = O_WSAO + (size_t)1024 * 1024;
  const size_t O_WKV  = O_WQ   + (size_t)1024 * 1024;
  const size_t O_WCAO = O_WKV  + (size_t)2048 * 1024;
  const size_t O_WFF1 = O_WCAO + (size_t)1024 * 1024;
  const size_t O_WFF2 = O_WFF1 + (size_t)4096 * 1024;
  const size_t O_XD   = O_WFF2 + (size_t)1024 * 4096;
  const size_t O_XE   = O_XD + 8388608;
  const size_t O_QKV  = O_XE + 8388608;
  const size_t O_QC   = O_QKV + 16777216;
  const size_t O_ATT  = O_QKV + 25165824;
  const size_t O_RES  = O_ATT + 8388608;
  const size_t O_RES2 = O_RES + 8388608;
  const size_t O_FF1  = O_RES2 + 8388608;
  const size_t O_VT   = O_FF1;
  const size_t O_VT2  = O_FF1 + 8388608;
  const size_t O_GO   = O_FF1 + 33554432;
  float* Pf = (float*)(Wb + O_QKV);

  k_cvt<<<8192, 256, 0, stream>>>(x_dec, Wb + O_XD, 2097152);
  k_cvt<<<8192, 256, 0, stream>>>(x_enc, Wb + O_XE, 2097152);
  k_transpose_cvt<<<dim3(96, 32),  256, 0, stream>>>(qkv_w,  Wb + O_WQKV, 1024, 3072);
  k_transpose_cvt<<<dim3(32, 32),  256, 0, stream>>>(sa_o_w, Wb + O_WSAO, 1024, 1024);
  k_transpose_cvt<<<dim3(32, 32),  256, 0, stream>>>(q_w,    Wb + O_WQ,   1024, 1024);
  k_transpose_cvt<<<dim3(64, 32),  256, 0, stream>>>(kv_w,   Wb + O_WKV,  1024, 2048);
  k_transpose_cvt<<<dim3(32, 32),  256, 0, stream>>>(ca_o_w, Wb + O_WCAO, 1024, 1024);
  k_transpose_cvt<<<dim3(128, 32), 256, 0, stream>>>(ff_w1,  Wb + O_WFF1, 1024, 4096);
  k_transpose_cvt<<<dim3(32, 128), 256, 0, stream>>>(ff_w2,  Wb + O_WFF2, 4096, 1024);

  // self-attention branch
  k_gemm256<0><<<dim3(32, 12), 512, 0, stream>>>(Wb + O_XD, Wb + O_WQKV, qkv_b,
                                                 Wb + O_QKV, 8192, 3072, 1024);
  k_vtrans<<<dim3(32, 64), 256, 0, stream>>>(Wb + O_QKV + 128, Wb + O_VT,
                                             (long long)2048 * 3072, 192, 3072, 2048);
  k_flash2<<<dim3(64, 8), 512, 0, stream>>>(Wb + O_QKV, Wb + O_QKV + 64, Wb + O_VT,
                                            Wb + O_ATT,
                                            (long long)2048 * 3072, 192, 3072,
                                            (long long)2048 * 3072, 192, 3072,
                                            (long long)2048 * 1024, 64, 1024, 2048);
  k_gemm_bt<0><<<dim3(64, 8), 256, 0, stream>>>(Wb + O_ATT, Wb + O_WSAO, sa_o_b,
                                                Wb + O_GO, 8192, 1024, 1024);
  k_add_ln<float, u16><<<8192, 256, 0, stream>>>(Wb + O_GO, x_dec, g1, be1, Wb + O_RES);

  // cross-attention branch
  k_gemm256<0><<<dim3(32, 8), 512, 0, stream>>>(Wb + O_XE, Wb + O_WKV, kv_b,
                                                Wb + O_QKV, 8192, 2048, 1024);
  k_vtrans<<<dim3(32, 64), 256, 0, stream>>>(Wb + O_QKV + 64, Wb + O_VT2,
                                             (long long)2048 * 2048, 128, 2048, 2048);
  k_gemm_bt<0><<<dim3(64, 8), 256, 0, stream>>>(Wb + O_RES, Wb + O_WQ, q_b,
                                                Wb + O_QC, 8192, 1024, 1024);
  k_flash2<<<dim3(64, 8), 512, 0, stream>>>(Wb + O_QC, Wb + O_QKV, Wb + O_VT2,
                                            Wb + O_ATT,
                                            (long long)2048 * 1024, 64, 1024,
                                            (long long)2048 * 2048, 128, 2048,
                                            (long long)2048 * 1024, 64, 1024, 2048);
  k_gemm_bt<0><<<dim3(64, 8), 256, 0, stream>>>(Wb + O_ATT, Wb + O_WCAO, ca_o_b,
                                                Wb + O_GO, 8192, 1024, 1024);
  k_add_ln<u16, u16><<<8192, 256, 0, stream>>>(Wb + O_GO, Wb + O_RES, g2, be2, Wb + O_RES2);

  // feed-forward: ff1 (gemm256) -> ff2 (split-K=2 on gemm256 skeleton) -> fused LN
  k_gemm256<1><<<dim3(32, 16), 512, 0, stream>>>(Wb + O_RES2, Wb + O_WFF1, ff_b1,
                                                 Wb + O_FF1, 8192, 4096, 1024);
  k_gemm256sk<<<dim3(32, 4, 2), 512, 0, stream>>>(Wb + O_FF1, Wb + O_WFF2, Pf,
                                                  8192, 1024, 4096, 2048);
  k_add_ln_ff<<<8192, 256, 0, stream>>>(Pf, Pf + 8388608, ff_b2, Wb + O_RES2,
                                        g3, be3, out);
}

// Round 24
// 565.468 us; speedup vs baseline: 1.0304x; 1.0304x over previous
//
#include <hip/hip_runtime.h>

typedef unsigned short u16;
typedef unsigned int   u32;
typedef __bf16 bf16_t;
typedef bf16_t bf16x4 __attribute__((ext_vector_type(4)));
typedef bf16_t bf16x8 __attribute__((ext_vector_type(8)));
typedef float  f32x4  __attribute__((ext_vector_type(4)));

// ---------- fp32 <-> bf16 helpers (RNE) ----------
__device__ __forceinline__ u16 f2bf(float f) {
  u32 u = __builtin_bit_cast(u32, f);
  u32 r = u + 0x7fffu + ((u >> 16) & 1u);
  return (u16)(r >> 16);
}
__device__ __forceinline__ float bf2f(u16 h) {
  u32 u = ((u32)h) << 16;
  return __builtin_bit_cast(float, u);
}

// async global->LDS, 16B per lane. LDS dest is wave-uniform base + lane*16.
__device__ __forceinline__ void gl_lds16(const u16* g, u16* l) {
  __builtin_amdgcn_global_load_lds(
      (const __attribute__((address_space(1))) u32*)g,
      (__attribute__((address_space(3))) u32*)l, 16, 0, 0);
}

// ---------- elementwise fp32 -> bf16 convert (4 el/thread) ----------
__global__ __launch_bounds__(256) void k_cvt(const float* __restrict__ in,
                                             u16* __restrict__ out, long n4) {
  long i = (long)blockIdx.x * 256 + threadIdx.x;
  if (i >= n4) return;
  float4 v = reinterpret_cast<const float4*>(in)[i];
  ushort4 o;
  o.x = f2bf(v.x); o.y = f2bf(v.y); o.z = f2bf(v.z); o.w = f2bf(v.w);
  reinterpret_cast<ushort4*>(out)[i] = o;
}

// ---------- W[K][N] fp32 -> Wt[N][K] bf16 (32x32 tiles) ----------
__global__ __launch_bounds__(256) void k_transpose_cvt(const float* __restrict__ W,
                                                       u16* __restrict__ Wt,
                                                       int K, int N) {
  __shared__ u16 tile[32][33];
  int n0 = blockIdx.x * 32, k0 = blockIdx.y * 32;
  int tx = threadIdx.x & 31, ty = threadIdx.x >> 5;
#pragma unroll
  for (int i = 0; i < 4; ++i) {
    int k = ty + i * 8;
    tile[k][tx] = f2bf(W[(size_t)(k0 + k) * N + n0 + tx]);
  }
  __syncthreads();
#pragma unroll
  for (int i = 0; i < 4; ++i) {
    int n = ty + i * 8;
    Wt[(size_t)(n0 + n) * K + k0 + tx] = tile[tx][n];
  }
}

// ---------- bf16 V[key][64] (strided) -> Vt[64][Tk] per head ----------
__global__ __launch_bounds__(256) void k_vtrans(const u16* __restrict__ in,
                                                u16* __restrict__ out,
                                                long long ibs, int ihs, int irs,
                                                int Tk) {
  __shared__ u16 t[64][72];
  const int tid = threadIdx.x;
  const int head = blockIdx.y;
  const int b = head >> 4, h = head & 15;
  const int kt = blockIdx.x * 64;
  const u16* ip = in + (size_t)b * ibs + (size_t)h * ihs;
  u16* op = out + (size_t)head * 64 * Tk;
#pragma unroll
  for (int i = 0; i < 2; ++i) {
    int c = i * 256 + tid;
    int key = c >> 3, d = (c & 7) * 8;
    *reinterpret_cast<uint4*>(&t[key][d]) =
        *reinterpret_cast<const uint4*>(ip + (size_t)(kt + key) * irs + d);
  }
  __syncthreads();
#pragma unroll
  for (int i = 0; i < 2; ++i) {
    int c = i * 256 + tid;
    int d = c >> 3, k8 = (c & 7) * 8;
    ushort4 lo, hi;
    lo.x = t[k8 + 0][d]; lo.y = t[k8 + 1][d]; lo.z = t[k8 + 2][d]; lo.w = t[k8 + 3][d];
    hi.x = t[k8 + 4][d]; hi.y = t[k8 + 5][d]; hi.z = t[k8 + 6][d]; hi.w = t[k8 + 7][d];
    uint4 o;
    o.x = ((u32)lo.y << 16) | lo.x; o.y = ((u32)lo.w << 16) | lo.z;
    o.z = ((u32)hi.y << 16) | hi.x; o.w = ((u32)hi.w << 16) | hi.z;
    *reinterpret_cast<uint4*>(op + (size_t)d * Tk + kt + k8) = o;
  }
}

// ---------- GEMM 128x128: 2-phase double-buffered gload_lds ----------
template<int RELU>
__global__ __launch_bounds__(256) void k_gemm_bt(
    const u16* __restrict__ A, const u16* __restrict__ Bt,
    const float* __restrict__ bias, u16* __restrict__ C,
    int M, int N, int K)
{
  __shared__ __align__(16) u16 As[2][128 * 64];
  __shared__ __align__(16) u16 Bs[2][128 * 64];
  const int tid = threadIdx.x;
  const int lane = tid & 63, wid = tid >> 6;
  const int wr = wid >> 1, wc = wid & 1;
  const int l15 = lane & 15, g = lane >> 4;
  const int bm = blockIdx.x * 128, bn = blockIdx.y * 128;
  const int srow = lane >> 3, scol = (lane & 7) * 8;

  f32x4 acc[4][4] = {};

  auto stage = [&](int buf, int kt) {
#pragma unroll
    for (int i = 0; i < 4; ++i) {
      int ch = wid * 4 + i;                     // chunk: 8 rows of 64
      gl_lds16(A  + (size_t)(bm + ch * 8 + srow) * K + kt + scol, &As[buf][ch * 512]);
      gl_lds16(Bt + (size_t)(bn + ch * 8 + srow) * K + kt + scol, &Bs[buf][ch * 512]);
    }
  };

  stage(0, 0);
  __syncthreads();
  int cur = 0;
  for (int kt = 0; kt < K; kt += 64) {
    if (kt + 64 < K) stage(cur ^ 1, kt + 64);   // loads fly across MFMA below
#pragma unroll
    for (int ks = 0; ks < 2; ++ks) {
      bf16x8 af[4], bfr[4];
#pragma unroll
      for (int m = 0; m < 4; ++m)
        af[m] = *reinterpret_cast<const bf16x8*>(&As[cur][(wr * 64 + m * 16 + l15) * 64 + ks * 32 + g * 8]);
#pragma unroll
      for (int n = 0; n < 4; ++n)
        bfr[n] = *reinterpret_cast<const bf16x8*>(&Bs[cur][(wc * 64 + n * 16 + l15) * 64 + ks * 32 + g * 8]);
      __builtin_amdgcn_s_setprio(1);
#pragma unroll
      for (int m = 0; m < 4; ++m)
#pragma unroll
        for (int n = 0; n < 4; ++n)
          acc[m][n] = __builtin_amdgcn_mfma_f32_16x16x32_bf16(af[m], bfr[n], acc[m][n], 0, 0, 0);
      __builtin_amdgcn_s_setprio(0);
    }
    __syncthreads();
    cur ^= 1;
  }
  // epilogue: preload bias per n, store row-sequential
  float bv[4];
#pragma unroll
  for (int n = 0; n < 4; ++n) bv[n] = bias[bn + wc * 64 + n * 16 + l15];
#pragma unroll
  for (int m = 0; m < 4; ++m)
#pragma unroll
    for (int r = 0; r < 4; ++r) {
      int row = bm + wr * 64 + m * 16 + g * 4 + r;
#pragma unroll
      for (int n = 0; n < 4; ++n) {
        float v = acc[m][n][r] + bv[n];
        if (RELU) v = fmaxf(v, 0.f);
        C[(size_t)row * N + bn + wc * 64 + n * 16 + l15] = f2bf(v);
      }
    }
}

// ---------- GEMM 256x256, 8 waves, counted-vmcnt 4-phase + T2 XOR swizzle ----------
template<int RELU>
__global__ __launch_bounds__(512, 1) void k_gemm256(
    const u16* __restrict__ A, const u16* __restrict__ Bt,
    const float* __restrict__ bias, u16* __restrict__ C,
    int M, int N, int K)
{
  __shared__ __align__(16) u16 lds[65536];      // 128 KiB: [buf][A|B][slab][64x64]
  const int tid = threadIdx.x;
  const int lane = tid & 63, wid = tid >> 6;
  const int wr = wid >> 2, wc = wid & 3;        // 2 x 4 wave grid
  const int l15 = lane & 15, g = lane >> 4;
  const int bm = blockIdx.x * 256, bn = blockIdx.y * 256;
  const int srow = tid >> 3;                              // 0..63 within slab
  const int swcol = (((tid & 7) ^ ((tid >> 3) & 7)) * 8); // inverse-swizzled source col
  const int swr = l15 & 7;                                // read-side row xor key

  f32x4 acc[8][4] = {};

  auto stageA = [&](int buf, int j, int kt) {
    gl_lds16(A + (size_t)(bm + j * 64 + srow) * K + kt + swcol,
             lds + buf * 32768 + j * 4096 + wid * 512);
  };
  auto stageB = [&](int buf, int j, int kt) {
    gl_lds16(Bt + (size_t)(bn + j * 64 + srow) * K + kt + swcol,
             lds + buf * 32768 + 16384 + j * 4096 + wid * 512);
  };

  // prologue: tile 0, steady-state issue order
  stageB(0, 0, 0); stageB(0, 1, 0); stageB(0, 2, 0); stageB(0, 3, 0);
  stageA(0, 0, 0); stageA(0, 2, 0); stageA(0, 1, 0); stageA(0, 3, 0);
  asm volatile("s_waitcnt vmcnt(2)" ::: "memory");
  __builtin_amdgcn_s_barrier();

  int cur = 0;
  for (int kt = 0; kt < K; kt += 64) {
    const u16* Ab = lds + cur * 32768;
    const u16* Bb = lds + cur * 32768 + 16384;
    const bool pre = (kt + 64 < K);
    const int nb = cur ^ 1;
    bf16x8 af[4][2], bflo[2][2], bfhi[2][2];

    // ---- phase 0: m0-3 x n0-1 ; issue B0,B1(t+1) ----
#pragma unroll
    for (int m = 0; m < 4; ++m)
#pragma unroll
      for (int ks = 0; ks < 2; ++ks)
        af[m][ks] = *reinterpret_cast<const bf16x8*>(
            &Ab[(2 * wr) * 4096 + (m * 16 + l15) * 64 + (((ks * 4 + g) ^ swr) * 8)]);
#pragma unroll
    for (int n = 0; n < 2; ++n)
#pragma unroll
      for (int ks = 0; ks < 2; ++ks)
        bflo[n][ks] = *reinterpret_cast<const bf16x8*>(
            &Bb[wc * 4096 + (n * 16 + l15) * 64 + (((ks * 4 + g) ^ swr) * 8)]);
    if (pre) { stageB(nb, 0, kt + 64); stageB(nb, 1, kt + 64); }
    __builtin_amdgcn_s_setprio(1);
#pragma unroll
    for (int m = 0; m < 4; ++m)
#pragma unroll
      for (int n = 0; n < 2; ++n)
#pragma unroll
        for (int ks = 0; ks < 2; ++ks)
          acc[m][n] = __builtin_amdgcn_mfma_f32_16x16x32_bf16(af[m][ks], bflo[n][ks], acc[m][n], 0, 0, 0);
    __builtin_amdgcn_s_setprio(0);
    __builtin_amdgcn_s_barrier();

    // ---- phase 1: m0-3 x n2-3 ; issue B2,B3(t+1) ; wait A1,A3(t) ----
#pragma unroll
    for (int n = 0; n < 2; ++n)
#pragma unroll
      for (int ks = 0; ks < 2; ++ks)
        bfhi[n][ks] = *reinterpret_cast<const bf16x8*>(
            &Bb[wc * 4096 + ((n + 2) * 16 + l15) * 64 + (((ks * 4 + g) ^ swr) * 8)]);
    if (pre) { stageB(nb, 2, kt + 64); stageB(nb, 3, kt + 64); }
    __builtin_amdgcn_s_setprio(1);
#pragma unroll
    for (int m = 0; m < 4; ++m)
#pragma unroll
      for (int n = 0; n < 2; ++n)
#pragma unroll
        for (int ks = 0; ks < 2; ++ks)
          acc[m][n + 2] = __builtin_amdgcn_mfma_f32_16x16x32_bf16(af[m][ks], bfhi[n][ks], acc[m][n + 2], 0, 0, 0);
    __builtin_amdgcn_s_setprio(0);
    if (pre) { asm volatile("s_waitcnt vmcnt(4)" ::: "memory"); }
    else     { asm volatile("s_waitcnt vmcnt(0)" ::: "memory"); }
    __builtin_amdgcn_s_barrier();

    // ---- phase 2: m4-7 x n2-3 (A slabs 2wr+1) ; issue A0,A2(t+1) ----
#pragma unroll
    for (int m = 0; m < 4; ++m)
#pragma unroll
      for (int ks = 0; ks < 2; ++ks)
        af[m][ks] = *reinterpret_cast<const bf16x8*>(
            &Ab[(2 * wr + 1) * 4096 + (m * 16 + l15) * 64 + (((ks * 4 + g) ^ swr) * 8)]);
    if (pre) { stageA(nb, 0, kt + 64); stageA(nb, 2, kt + 64); }
    __builtin_amdgcn_s_setprio(1);
#pragma unroll
    for (int m = 0; m < 4; ++m)
#pragma unroll
      for (int n = 0; n < 2; ++n)
#pragma unroll
        for (int ks = 0; ks < 2; ++ks)
          acc[m + 4][n + 2] = __builtin_amdgcn_mfma_f32_16x16x32_bf16(af[m][ks], bfhi[n][ks], acc[m + 4][n + 2], 0, 0, 0);
    __builtin_amdgcn_s_setprio(0);
    __builtin_amdgcn_s_barrier();

    // ---- phase 3: m4-7 x n0-1 ; issue A1,A3(t+1) ; boundary wait ----
    if (pre) { stageA(nb, 1, kt + 64); stageA(nb, 3, kt + 64); }
    __builtin_amdgcn_s_setprio(1);
#pragma unroll
    for (int m = 0; m < 4; ++m)
#pragma unroll
      for (int n = 0; n < 2; ++n)
#pragma unroll
        for (int ks = 0; ks < 2; ++ks)
          acc[m + 4][n] = __builtin_amdgcn_mfma_f32_16x16x32_bf16(af[m][ks], bflo[n][ks], acc[m + 4][n], 0, 0, 0);
    __builtin_amdgcn_s_setprio(0);
    asm volatile("s_waitcnt vmcnt(2)" ::: "memory");
    __builtin_amdgcn_s_barrier();
    cur ^= 1;
  }

  // epilogue: preload bias per n, store row-sequential (full-line coalescing)
  float bv[4];
#pragma unroll
  for (int n = 0; n < 4; ++n) bv[n] = bias[bn + wc * 64 + n * 16 + l15];
#pragma unroll
  for (int m = 0; m < 8; ++m)
#pragma unroll
    for (int r = 0; r < 4; ++r) {
      int row = bm + wr * 128 + m * 16 + g * 4 + r;
#pragma unroll
      for (int n = 0; n < 4; ++n) {
        float v = acc[m][n][r] + bv[n];
        if (RELU) v = fmaxf(v, 0.f);
        C[(size_t)row * N + bn + wc * 64 + n * 16 + l15] = f2bf(v);
      }
    }
}

// ---------- split-K GEMM 256x256 on the counted-vmcnt skeleton: f32 partials ----------
__global__ __launch_bounds__(512, 1) void k_gemm256sk(
    const u16* __restrict__ A, const u16* __restrict__ Bt,
    float* __restrict__ P,
    int M, int N, int Kfull, int Kchunk)
{
  __shared__ __align__(16) u16 lds[65536];
  const int tid = threadIdx.x;
  const int lane = tid & 63, wid = tid >> 6;
  const int wr = wid >> 2, wc = wid & 3;
  const int l15 = lane & 15, g = lane >> 4;
  const int bm = blockIdx.x * 256, bn = blockIdx.y * 256;
  const int k0 = blockIdx.z * Kchunk;
  float* Pz = P + (size_t)blockIdx.z * M * N;
  const int srow = tid >> 3;
  const int swcol = (((tid & 7) ^ ((tid >> 3) & 7)) * 8);
  const int swr = l15 & 7;

  f32x4 acc[8][4] = {};

  auto stageA = [&](int buf, int j, int kt) {
    gl_lds16(A + (size_t)(bm + j * 64 + srow) * Kfull + k0 + kt + swcol,
             lds + buf * 32768 + j * 4096 + wid * 512);
  };
  auto stageB = [&](int buf, int j, int kt) {
    gl_lds16(Bt + (size_t)(bn + j * 64 + srow) * Kfull + k0 + kt + swcol,
             lds + buf * 32768 + 16384 + j * 4096 + wid * 512);
  };

  stageB(0, 0, 0); stageB(0, 1, 0); stageB(0, 2, 0); stageB(0, 3, 0);
  stageA(0, 0, 0); stageA(0, 2, 0); stageA(0, 1, 0); stageA(0, 3, 0);
  asm volatile("s_waitcnt vmcnt(2)" ::: "memory");
  __builtin_amdgcn_s_barrier();

  int cur = 0;
  for (int kt = 0; kt < Kchunk; kt += 64) {
    const u16* Ab = lds + cur * 32768;
    const u16* Bb = lds + cur * 32768 + 16384;
    const bool pre = (kt + 64 < Kchunk);
    const int nb = cur ^ 1;
    bf16x8 af[4][2], bflo[2][2], bfhi[2][2];

    // ---- phase 0 ----
#pragma unroll
    for (int m = 0; m < 4; ++m)
#pragma unroll
      for (int ks = 0; ks < 2; ++ks)
        af[m][ks] = *reinterpret_cast<const bf16x8*>(
            &Ab[(2 * wr) * 4096 + (m * 16 + l15) * 64 + (((ks * 4 + g) ^ swr) * 8)]);
#pragma unroll
    for (int n = 0; n < 2; ++n)
#pragma unroll
      for (int ks = 0; ks < 2; ++ks)
        bflo[n][ks] = *reinterpret_cast<const bf16x8*>(
            &Bb[wc * 4096 + (n * 16 + l15) * 64 + (((ks * 4 + g) ^ swr) * 8)]);
    if (pre) { stageB(nb, 0, kt + 64); stageB(nb, 1, kt + 64); }
    __builtin_amdgcn_s_setprio(1);
#pragma unroll
    for (int m = 0; m < 4; ++m)
#pragma unroll
      for (int n = 0; n < 2; ++n)
#pragma unroll
        for (int ks = 0; ks < 2; ++ks)
          acc[m][n] = __builtin_amdgcn_mfma_f32_16x16x32_bf16(af[m][ks], bflo[n][ks], acc[m][n], 0, 0, 0);
    __builtin_amdgcn_s_setprio(0);
    __builtin_amdgcn_s_barrier();

    // ---- phase 1 ----
#pragma unroll
    for (int n = 0; n < 2; ++n)
#pragma unroll
      for (int ks = 0; ks < 2; ++ks)
        bfhi[n][ks] = *reinterpret_cast<const bf16x8*>(
            &Bb[wc * 4096 + ((n + 2) * 16 + l15) * 64 + (((ks * 4 + g) ^ swr) * 8)]);
    if (pre) { stageB(nb, 2, kt + 64); stageB(nb, 3, kt + 64); }
    __builtin_amdgcn_s_setprio(1);
#pragma unroll
    for (int m = 0; m < 4; ++m)
#pragma unroll
      for (int n = 0; n < 2; ++n)
#pragma unroll
        for (int ks = 0; ks < 2; ++ks)
          acc[m][n + 2] = __builtin_amdgcn_mfma_f32_16x16x32_bf16(af[m][ks], bfhi[n][ks], acc[m][n + 2], 0, 0, 0);
    __builtin_amdgcn_s_setprio(0);
    if (pre) { asm volatile("s_waitcnt vmcnt(4)" ::: "memory"); }
    else     { asm volatile("s_waitcnt vmcnt(0)" ::: "memory"); }
    __builtin_amdgcn_s_barrier();

    // ---- phase 2 ----
#pragma unroll
    for (int m = 0; m < 4; ++m)
#pragma unroll
      for (int ks = 0; ks < 2; ++ks)
        af[m][ks] = *reinterpret_cast<const bf16x8*>(
            &Ab[(2 * wr + 1) * 4096 + (m * 16 + l15) * 64 + (((ks * 4 + g) ^ swr) * 8)]);
    if (pre) { stageA(nb, 0, kt + 64); stageA(nb, 2, kt + 64); }
    __builtin_amdgcn_s_setprio(1);
#pragma unroll
    for (int m = 0; m < 4; ++m)
#pragma unroll
      for (int n = 0; n < 2; ++n)
#pragma unroll
        for (int ks = 0; ks < 2; ++ks)
          acc[m + 4][n + 2] = __builtin_amdgcn_mfma_f32_16x16x32_bf16(af[m][ks], bfhi[n][ks], acc[m + 4][n + 2], 0, 0, 0);
    __builtin_amdgcn_s_setprio(0);
    __builtin_amdgcn_s_barrier();

    // ---- phase 3 ----
    if (pre) { stageA(nb, 1, kt + 64); stageA(nb, 3, kt + 64); }
    __builtin_amdgcn_s_setprio(1);
#pragma unroll
    for (int m = 0; m < 4; ++m)
#pragma unroll
      for (int n = 0; n < 2; ++n)
#pragma unroll
        for (int ks = 0; ks < 2; ++ks)
          acc[m + 4][n] = __builtin_amdgcn_mfma_f32_16x16x32_bf16(af[m][ks], bflo[n][ks], acc[m + 4][n], 0, 0, 0);
    __builtin_amdgcn_s_setprio(0);
    asm volatile("s_waitcnt vmcnt(2)" ::: "memory");
    __builtin_amdgcn_s_barrier();
    cur ^= 1;
  }

  // epilogue: f32 partials, row-sequential
#pragma unroll
  for (int m = 0; m < 8; ++m)
#pragma unroll
    for (int r = 0; r < 4; ++r) {
      int row = bm + wr * 128 + m * 16 + g * 4 + r;
#pragma unroll
      for (int n = 0; n < 4; ++n)
        Pz[(size_t)row * N + bn + wc * 64 + n * 16 + l15] = acc[m][n][r];
    }
}

// ---------- flash attention v15 (banked, R22-proven): 8 waves, 2 qsets/wave ----------
__global__ __launch_bounds__(512) void k_flash2(
    const u16* __restrict__ Qg, const u16* __restrict__ Kg, const u16* __restrict__ VTg,
    u16* __restrict__ Og,
    long long qbs, int qhs, int qrs,
    long long kbs, int khs, int krs,
    long long obs, int ohs, int ors,
    int Tk)
{
  __shared__ __align__(16) u16 Ks[64][72];
  __shared__ __align__(16) u16 Vs[64][72];      // Vs[d][key]
  const int tid = threadIdx.x;
  const int lane = tid & 63, wid = tid >> 6;    // wid 0..7
  const int l15 = lane & 15, g = lane >> 4;
  const int head = blockIdx.x;                  // head on x -> XCD-local
  const int b = head >> 4, h = head & 15;
  const int srow = tid >> 3, scol = (tid & 7) * 8;   // 512 threads: 64 rows x 64 cols once

  const u16* Q  = Qg + (size_t)b * qbs + (size_t)h * qhs;
  const u16* Kp = Kg + (size_t)b * kbs + (size_t)h * khs;
  const u16* Vp = VTg + (size_t)head * 64 * Tk;
  u16* Op = Og + (size_t)b * obs + (size_t)h * ohs;

  const int q0 = blockIdx.y * 256 + wid * 32;  // wave owns rows [q0, q0+32)
  const float SCL = 0.125f * 1.44269504f;      // folded into Q below

  bf16x8 qf0[2], qf1[2];
#pragma unroll
  for (int ks = 0; ks < 2; ++ks) {
    bf16x8 r0 = *reinterpret_cast<const bf16x8*>(Q + (size_t)(q0 + l15) * qrs + ks * 32 + g * 8);
    bf16x8 r1 = *reinterpret_cast<const bf16x8*>(Q + (size_t)(q0 + 16 + l15) * qrs + ks * 32 + g * 8);
#pragma unroll
    for (int j = 0; j < 8; ++j) {
      qf0[ks][j] = (bf16_t)((float)r0[j] * SCL);
      qf1[ks][j] = (bf16_t)((float)r1[j] * SCL);
    }
  }
  bf16x8 ones;
#pragma unroll
  for (int j = 0; j < 8; ++j) ones[j] = (bf16_t)1.0f;

  f32x4 oacc0[4] = {}, oacc1[4] = {};
  f32x4 lacc0 = {}, lacc1 = {};

  uint4 ka, va, kb, vb;

  auto load_set = [&](int kt, uint4& k0, uint4& v0) {
    k0 = *reinterpret_cast<const uint4*>(Kp + (size_t)(kt + srow) * krs + scol);
    v0 = *reinterpret_cast<const uint4*>(Vp + (size_t)srow * Tk + kt + scol);
  };

  auto tile = [&](const uint4& k0, const uint4& v0,
                  int ktn, uint4& nk0, uint4& nv0) {
    __syncthreads();   // previous compute done reading LDS
    *reinterpret_cast<uint4*>(&Ks[srow][scol]) = k0;
    *reinterpret_cast<uint4*>(&Vs[srow][scol]) = v0;
    load_set(ktn, nk0, nv0);  // T14: next tile flies under compute
    __syncthreads();   // staging visible

    // QK^T for both qsets; each kf read feeds two MFMAs
    f32x4 sc0[4] = {}, sc1[4] = {};
    __builtin_amdgcn_s_setprio(1);
#pragma unroll
    for (int ks = 0; ks < 2; ++ks)
#pragma unroll
      for (int kb2 = 0; kb2 < 4; ++kb2) {
        bf16x8 kf = *reinterpret_cast<const bf16x8*>(&Ks[kb2 * 16 + l15][ks * 32 + g * 8]);
        sc0[kb2] = __builtin_amdgcn_mfma_f32_16x16x32_bf16(kf, qf0[ks], sc0[kb2], 0, 0, 0);
        sc1[kb2] = __builtin_amdgcn_mfma_f32_16x16x32_bf16(kf, qf1[ks], sc1[kb2], 0, 0, 0);
      }
    __builtin_amdgcn_s_setprio(0);

    // exp2 into per-kc register P fragments (slot bijection F(g,j))
    bf16x8 p0a, p0b, p1a, p1b;
#pragma unroll
    for (int r = 0; r < 4; ++r) {
      p0a[r]     = (bf16_t)__builtin_amdgcn_exp2f(sc0[0][r]);
      p0a[4 + r] = (bf16_t)__builtin_amdgcn_exp2f(sc0[1][r]);
      p0b[r]     = (bf16_t)__builtin_amdgcn_exp2f(sc0[2][r]);
      p0b[4 + r] = (bf16_t)__builtin_amdgcn_exp2f(sc0[3][r]);
      p1a[r]     = (bf16_t)__builtin_amdgcn_exp2f(sc1[0][r]);
      p1a[4 + r] = (bf16_t)__builtin_amdgcn_exp2f(sc1[1][r]);
      p1b[r]     = (bf16_t)__builtin_amdgcn_exp2f(sc1[2][r]);
      p1b[4 + r] = (bf16_t)__builtin_amdgcn_exp2f(sc1[3][r]);
    }

    // PV: vf assembled from two b64 Vs reads per (nb,kc); feeds both qsets
    __builtin_amdgcn_s_setprio(1);
#pragma unroll
    for (int kc = 0; kc < 2; ++kc) {
      const bf16x8& pf0 = kc ? p0b : p0a;
      const bf16x8& pf1 = kc ? p1b : p1a;
#pragma unroll
      for (int nb = 0; nb < 4; ++nb) {
        bf16x4 vlo = *reinterpret_cast<const bf16x4*>(&Vs[nb * 16 + l15][kc * 32 + 4 * g]);
        bf16x4 vhi = *reinterpret_cast<const bf16x4*>(&Vs[nb * 16 + l15][kc * 32 + 16 + 4 * g]);
        bf16x8 vf;
#pragma unroll
        for (int j = 0; j < 4; ++j) { vf[j] = vlo[j]; vf[4 + j] = vhi[j]; }
        oacc0[nb] = __builtin_amdgcn_mfma_f32_16x16x32_bf16(pf0, vf, oacc0[nb], 0, 0, 0);
        oacc1[nb] = __builtin_amdgcn_mfma_f32_16x16x32_bf16(pf1, vf, oacc1[nb], 0, 0, 0);
      }
      lacc0 = __builtin_amdgcn_mfma_f32_16x16x32_bf16(pf0, ones, lacc0, 0, 0, 0);
      lacc1 = __builtin_amdgcn_mfma_f32_16x16x32_bf16(pf1, ones, lacc1, 0, 0, 0);
    }
    __builtin_amdgcn_s_setprio(0);
  };

  load_set(0, ka, va);
  for (int kt = 0; kt < Tk; kt += 128) {
    tile(ka, va, kt + 64, kb, vb);
    int ktn = (kt + 128 < Tk) ? kt + 128 : 0;   // last prefetch harmless
    tile(kb, vb, ktn, ka, va);
  }

  // epilogue: lacc[r] holds l for qrow 4g+r directly
#pragma unroll
  for (int r = 0; r < 4; ++r) {
    float inv0 = 1.f / lacc0[r];
    float inv1 = 1.f / lacc1[r];
#pragma unroll
    for (int nb = 0; nb < 4; ++nb) {
      Op[(size_t)(q0 + g * 4 + r) * ors + nb * 16 + l15]      = f2bf(oacc0[nb][r] * inv0);
      Op[(size_t)(q0 + 16 + g * 4 + r) * ors + nb * 16 + l15] = f2bf(oacc1[nb][r] * inv1);
    }
  }
}

// ---------- fused add + LayerNorm over D=1024 (one row per block) ----------
__device__ __forceinline__ void load4v(const float* p, float* v) {
  float4 t = *reinterpret_cast<const float4*>(p);
  v[0] = t.x; v[1] = t.y; v[2] = t.z; v[3] = t.w;
}
__device__ __forceinline__ void load4v(const u16* p, float* v) {
  ushort4 t = *reinterpret_cast<const ushort4*>(p);
  v[0] = bf2f(t.x); v[1] = bf2f(t.y); v[2] = bf2f(t.z); v[3] = bf2f(t.w);
}
__device__ __forceinline__ void store4v(float* p, const float* v) {
  float4 t; t.x = v[0]; t.y = v[1]; t.z = v[2]; t.w = v[3];
  *reinterpret_cast<float4*>(p) = t;
}
__device__ __forceinline__ void store4v(u16* p, const float* v) {
  ushort4 t; t.x = f2bf(v[0]); t.y = f2bf(v[1]); t.z = f2bf(v[2]); t.w = f2bf(v[3]);
  *reinterpret_cast<ushort4*>(p) = t;
}

__device__ __forceinline__ void ln_core(float* v, int tid, const float* gamma,
                                        const float* beta, float* o) {
  float s = v[0] + v[1] + v[2] + v[3];
  float q = v[0]*v[0] + v[1]*v[1] + v[2]*v[2] + v[3]*v[3];
#pragma unroll
  for (int off = 32; off > 0; off >>= 1) {
    s += __shfl_down(s, off);
    q += __shfl_down(q, off);
  }
  __shared__ float sh[8];
  const int lane = tid & 63, wid = tid >> 6;
  if (lane == 0) { sh[wid] = s; sh[4 + wid] = q; }
  __syncthreads();
  s = sh[0] + sh[1] + sh[2] + sh[3];
  q = sh[4] + sh[5] + sh[6] + sh[7];
  float mean = s * (1.f / 1024.f);
  float var = q * (1.f / 1024.f) - mean * mean;
  float inv = 1.f / sqrtf(var + 1e-5f);
  float gv[4], bv[4];
  load4v(gamma + tid * 4, gv);
  load4v(beta + tid * 4, bv);
#pragma unroll
  for (int j = 0; j < 4; ++j) o[j] = gv[j] * (v[j] - mean) * inv + bv[j];
}

template<typename TRES, typename TOUT>
__global__ __launch_bounds__(256) void k_add_ln(
    const u16* __restrict__ X, const TRES* __restrict__ R,
    const float* __restrict__ gamma, const float* __restrict__ beta,
    TOUT* __restrict__ Out)
{
  const int row = blockIdx.x;
  const int tid = threadIdx.x;
  const size_t base = (size_t)row * 1024 + tid * 4;
  float x[4], rr[4], v[4], o[4];
  load4v(X + base, x);
  load4v(R + base, rr);
#pragma unroll
  for (int j = 0; j < 4; ++j) v[j] = x[j] + rr[j];
  ln_core(v, tid, gamma, beta, o);
  store4v(Out + base, o);
}

// sum of 2 f32 split-K partials + bias + residual, then LN -> f32 out
__global__ __launch_bounds__(256) void k_add_ln_ff(
    const float* __restrict__ P0, const float* __restrict__ P1,
    const float* __restrict__ bias, const u16* __restrict__ R,
    const float* __restrict__ gamma, const float* __restrict__ beta,
    float* __restrict__ Out)
{
  const int row = blockIdx.x;
  const int tid = threadIdx.x;
  const size_t base = (size_t)row * 1024 + tid * 4;
  float p0[4], p1[4], bb[4], rr[4], v[4], o[4];
  load4v(P0 + base, p0);
  load4v(P1 + base, p1);
  load4v(bias + tid * 4, bb);
  load4v(R + base, rr);
#pragma unroll
  for (int j = 0; j < 4; ++j) v[j] = p0[j] + p1[j] + bb[j] + rr[j];
  ln_core(v, tid, gamma, beta, o);
  store4v(Out + base, o);
}

// ---------- driver ----------
extern "C" void kernel_launch(void* const* d_in, const int* in_sizes, int n_in,
                              void* d_out, int out_size, void* d_ws, size_t ws_size,
                              hipStream_t stream)
{
  (void)in_sizes; (void)n_in; (void)out_size; (void)ws_size;
  const float* x_enc  = (const float*)d_in[0];
  const float* x_dec  = (const float*)d_in[1];
  const float* qkv_w  = (const float*)d_in[2];
  const float* qkv_b  = (const float*)d_in[3];
  const float* sa_o_w = (const float*)d_in[4];
  const float* sa_o_b = (const float*)d_in[5];
  const float* g1     = (const float*)d_in[6];
  const float* be1    = (const float*)d_in[7];
  const float* q_w    = (const float*)d_in[8];
  const float* q_b    = (const float*)d_in[9];
  const float* kv_w   = (const float*)d_in[10];
  const float* kv_b   = (const float*)d_in[11];
  const float* ca_o_w = (const float*)d_in[12];
  const float* ca_o_b = (const float*)d_in[13];
  const float* g2     = (const float*)d_in[14];
  const float* be2    = (const float*)d_in[15];
  const float* ff_w1  = (const float*)d_in[16];
  const float* ff_b1  = (const float*)d_in[17];
  const float* ff_w2  = (const float*)d_in[18];
  const float* ff_b2  = (const float*)d_in[19];
  const float* g3     = (const float*)d_in[20];
  const float* be3    = (const float*)d_in[21];
  float* out = (float*)d_out;

  u16* Wb = (u16*)d_ws;
  const size_t O_WQKV = 0;
  const size_t O_WSAO = O_WQKV + (size_t)3072 * 1024;
  const size_t O_WQ   = O_WSAO + (size_t)1024 * 1024;
  const size_t O_WKV  = O_WQ   + (size_t)1024 * 1024;
  const size_t O_WCAO = O_WKV  + (size_t)2048 * 1024;
  const size_t O_WFF1 = O_WCAO + (size_t)1024 * 1024;
  const size_t O_WFF2 = O_WFF1 + (size_t)4096 * 1024;
  const size_t O_XD   = O_WFF2 + (size_t)1024 * 4096;
  const size_t O_XE   = O_XD + 8388608;
  const size_t O_QKV  = O_XE + 8388608;
  const size_t O_QC   = O_QKV + 16777216;
  const size_t O_ATT  = O_QKV + 25165824;
  const size_t O_RES  = O_ATT + 8388608;
  const size_t O_RES2 = O_RES + 8388608;
  const size_t O_FF1  = O_RES2 + 8388608;
  const size_t O_VT   = O_FF1;
  const size_t O_VT2  = O_FF1 + 8388608;
  const size_t O_GO   = O_FF1 + 33554432;
  float* Pf = (float*)(Wb + O_QKV);

  k_cvt<<<8192, 256, 0, stream>>>(x_dec, Wb + O_XD, 2097152);
  k_cvt<<<8192, 256, 0, stream>>>(x_enc, Wb + O_XE, 2097152);
  k_transpose_cvt<<<dim3(96, 32),  256, 0, stream>>>(qkv_w,  Wb + O_WQKV, 1024, 3072);
  k_transpose_cvt<<<dim3(32, 32),  256, 0, stream>>>(sa_o_w, Wb + O_WSAO, 1024, 1024);
  k_transpose_cvt<<<dim3(32, 32),  256, 0, stream>>>(q_w,    Wb + O_WQ,   1024, 1024);
  k_transpose_cvt<<<dim3(64, 32),  256, 0, stream>>>(kv_w,   Wb + O_WKV,  1024, 2048);
  k_transpose_cvt<<<dim3(32, 32),  256, 0, stream>>>(ca_o_w, Wb + O_WCAO, 1024, 1024);
  k_transpose_cvt<<<dim3(128, 32), 256, 0, stream>>>(ff_w1,  Wb + O_WFF1, 1024, 4096);
  k_transpose_cvt<<<dim3(32, 128), 256, 0, stream>>>(ff_w2,  Wb + O_WFF2, 4096, 1024);

  // self-attention branch
  k_gemm256<0><<<dim3(32, 12), 512, 0, stream>>>(Wb + O_XD, Wb + O_WQKV, qkv_b,
                                                 Wb + O_QKV, 8192, 3072, 1024);
  k_vtrans<<<dim3(32, 64), 256, 0, stream>>>(Wb + O_QKV + 128, Wb + O_VT,
                                             (long long)2048 * 3072, 192, 3072, 2048);
  k_flash2<<<dim3(64, 8), 512, 0, stream>>>(Wb + O_QKV, Wb + O_QKV + 64, Wb + O_VT,
                                            Wb + O_ATT,
                                            (long long)2048 * 3072, 192, 3072,
                                            (long long)2048 * 3072, 192, 3072,
                                            (long long)2048 * 1024, 64, 1024, 2048);
  k_gemm_bt<0><<<dim3(64, 8), 256, 0, stream>>>(Wb + O_ATT, Wb + O_WSAO, sa_o_b,
                                                Wb + O_GO, 8192, 1024, 1024);
  k_add_ln<float, u16><<<8192, 256, 0, stream>>>(Wb + O_GO, x_dec, g1, be1, Wb + O_RES);

  // cross-attention branch
  k_gemm256<0><<<dim3(32, 8), 512, 0, stream>>>(Wb + O_XE, Wb + O_WKV, kv_b,
                                                Wb + O_QKV, 8192, 2048, 1024);
  k_vtrans<<<dim3(32, 64), 256, 0, stream>>>(Wb + O_QKV + 64, Wb + O_VT2,
                                             (long long)2048 * 2048, 128, 2048, 2048);
  k_gemm_bt<0><<<dim3(64, 8), 256, 0, stream>>>(Wb + O_RES, Wb + O_WQ, q_b,
                                                Wb + O_QC, 8192, 1024, 1024);
  k_flash2<<<dim3(64, 8), 512, 0, stream>>>(Wb + O_QC, Wb + O_QKV, Wb + O_VT2,
                                            Wb + O_ATT,
                                            (long long)2048 * 1024, 64, 1024,
                                            (long long)2048 * 2048, 128, 2048,
                                            (long long)2048 * 1024, 64, 1024, 2048);
  k_gemm_bt<0><<<dim3(64, 8), 256, 0, stream>>>(Wb + O_ATT, Wb + O_WCAO, ca_o_b,
                                                Wb + O_GO, 8192, 1024, 1024);
  k_add_ln<u16, u16><<<8192, 256, 0, stream>>>(Wb + O_GO, Wb + O_RES, g2, be2, Wb + O_RES2);

  // feed-forward: ff1 (gemm256) -> ff2 (split-K=2 on gemm256 skeleton) -> fused LN
  k_gemm256<1><<<dim3(32, 16), 512, 0, stream>>>(Wb + O_RES2, Wb + O_WFF1, ff_b1,
                                                 Wb + O_FF1, 8192, 4096, 1024);
  k_gemm256sk<<<dim3(32, 4, 2), 512, 0, stream>>>(Wb + O_FF1, Wb + O_WFF2, Pf,
                                                  8192, 1024, 4096, 2048);
  k_add_ln_ff<<<8192, 256, 0, stream>>>(Pf, Pf + 8388608, ff_b2, Wb + O_RES2,
                                        g3, be3, out);
}